// Round 1
// baseline (396.175 us; speedup 1.0000x reference)
//
#include <hip/hip_runtime.h>

// Problem constants: B=2, S=2048, D=2048, H=16, DH=128
#define B_  2
#define S_  2048
#define D_  2048
#define H_  16
#define DH_ 128
#define M_  (B_ * S_)          // 4096 rows of x / q / k / v (flattened b,s)

typedef __bf16 bf16;
typedef __bf16 bf16x2 __attribute__((ext_vector_type(2)));
typedef __bf16 bf16x4 __attribute__((ext_vector_type(4)));
typedef __bf16 bf16x8 __attribute__((ext_vector_type(8)));
typedef float  f32x4  __attribute__((ext_vector_type(4)));

static constexpr float kScale = 0.08838834764831845f;  // DH^-0.5, folded into Q at RoPE

__device__ __forceinline__ void async16(const void* g, void* l) {
  // 16B-wide global->LDS direct copy (wave-uniform base + lane*16 on LDS side)
  __builtin_amdgcn_global_load_lds(
      (const __attribute__((address_space(1))) void*)g,
      (__attribute__((address_space(3))) void*)l, 16, 0, 0);
}

// ---------------------------------------------------------------------------
// fp32 -> bf16 conversion, 4 elems/thread (n must be multiple of 1024)
__global__ void cvt_bf16(const float* __restrict__ s, bf16* __restrict__ d) {
  int i = (blockIdx.x * 256 + threadIdx.x) * 4;
  float4 v = *(const float4*)(s + i);
  bf16x4 o = {(bf16)v.x, (bf16)v.y, (bf16)v.z, (bf16)v.w};
  *(bf16x4*)(d + i) = o;
}

// ---------------------------------------------------------------------------
// GEMM1: C = A(4096x2048) * B^T, B = concat(Wq,Wk,Wv) (6144x2048), epilogue
// scatters Q,K into [B,H,S,DH] bf16 and V into [B,S,D] bf16.
__global__ __launch_bounds__(256, 2) void gemm_qkv(
    const bf16* __restrict__ A, const bf16* __restrict__ Bm,
    bf16* __restrict__ qb, bf16* __restrict__ kb, bf16* __restrict__ vb) {
  __shared__ alignas(16) bf16 As[128 * 32];
  __shared__ alignas(16) bf16 Bs[128 * 32];
  const int tid = threadIdx.x;
  const int lane = tid & 63, wv = tid >> 6;
  const int quad = lane >> 4, c16 = lane & 15;
  const int wm = (wv >> 1) * 64, wn = (wv & 1) * 64;
  const int m0 = blockIdx.y * 128, n0 = blockIdx.x * 128;

  const bf16* ag = A  + (size_t)(m0 + (tid >> 2)) * D_ + (tid & 3) * 8;
  const bf16* bg = Bm + (size_t)(n0 + (tid >> 2)) * D_ + (tid & 3) * 8;
  char* asl = (char*)As + tid * 16;
  char* bsl = (char*)Bs + tid * 16;

  f32x4 acc[4][4] = {};
  for (int k0 = 0; k0 < D_; k0 += 32) {
    __syncthreads();
    async16(ag + k0,            asl);
    async16(ag + k0 + 64 * D_,  asl + 4096);
    async16(bg + k0,            bsl);
    async16(bg + k0 + 64 * D_,  bsl + 4096);
    __syncthreads();
    bf16x8 af[4], bfr[4];
#pragma unroll
    for (int i = 0; i < 4; ++i)
      af[i] = *(const bf16x8*)(As + (wm + i * 16 + c16) * 32 + quad * 8);
#pragma unroll
    for (int j = 0; j < 4; ++j)
      bfr[j] = *(const bf16x8*)(Bs + (wn + j * 16 + c16) * 32 + quad * 8);
#pragma unroll
    for (int i = 0; i < 4; ++i)
#pragma unroll
      for (int j = 0; j < 4; ++j)
        acc[i][j] = __builtin_amdgcn_mfma_f32_16x16x32_bf16(af[i], bfr[j], acc[i][j], 0, 0, 0);
  }

#pragma unroll
  for (int i = 0; i < 4; ++i)
#pragma unroll
    for (int j = 0; j < 4; ++j)
#pragma unroll
      for (int r = 0; r < 4; ++r) {
        int gm = m0 + wm + i * 16 + quad * 4 + r;   // row of x (b*2048+s)
        int gn = n0 + wn + j * 16 + c16;            // col in [0,6144)
        float v = acc[i][j][r];
        int b = gm >> 11, s = gm & 2047;
        if (gn < 2048) {                                  // Q
          int h = gn >> 7, d = gn & 127;
          qb[(size_t)((b * 16 + h) * 2048 + s) * 128 + d] = (bf16)v;
        } else if (gn < 4096) {                           // K
          int h = (gn - 2048) >> 7, d = gn & 127;
          kb[(size_t)((b * 16 + h) * 2048 + s) * 128 + d] = (bf16)v;
        } else {                                          // V, [b,s,d] layout
          vb[(size_t)gm * 2048 + (gn - 4096)] = (bf16)v;
        }
      }
}

// ---------------------------------------------------------------------------
// RoPE in-place on Q,K [B,H,S,DH] bf16; Q also scaled by DH^-0.5.
__global__ void rope_kernel(bf16* __restrict__ q, bf16* __restrict__ k,
                            const float* __restrict__ cb, const float* __restrict__ sb) {
  int p  = blockIdx.x * 256 + threadIdx.x;     // pair index, < B*H*S*64
  int si = p & (S_ * 64 - 1);                  // s*64 + i
  float c = cb[si], sn = sb[si];
  bf16x2* qp = (bf16x2*)q + p;
  bf16x2 qv = *qp;
  float te = (float)qv[0], to = (float)qv[1];
  bf16x2 oq = {(bf16)((te * c - to * sn) * kScale), (bf16)((te * sn + to * c) * kScale)};
  *qp = oq;
  bf16x2* kp = (bf16x2*)k + p;
  bf16x2 kv = *kp;
  te = (float)kv[0]; to = (float)kv[1];
  bf16x2 ok = {(bf16)(te * c - to * sn), (bf16)(te * sn + to * c)};
  *kp = ok;
}

// ---------------------------------------------------------------------------
// Per (b,h): lse[s] = log sum_k exp(q_s . k_k)  (scale already in Q),
// diag[s] = q_s . k_s. Q-tile (128 rows) resident in LDS; sweep K tiles.
// LDS layout = 4 sub-tiles of [128][32] (same pattern as the GEMM) to keep
// ds_read_b128 bank behavior identical to the m97 structure.
__global__ __launch_bounds__(256, 2) void score_lse(
    const bf16* __restrict__ qb, const bf16* __restrict__ kb,
    float* __restrict__ lse, float* __restrict__ diag) {
  __shared__ alignas(16) bf16 Qs[4 * 128 * 32];  // 32KB
  __shared__ alignas(16) bf16 Ks[4 * 128 * 32];  // 32KB
  const int tid = threadIdx.x;
  const int lane = tid & 63, wv = tid >> 6;
  const int quad = lane >> 4, c16 = lane & 15;
  const int wm = wv * 32;                 // each wave owns 32 distinct Q rows
  const int bh = blockIdx.y;
  const int m0 = blockIdx.x * 128;
  const bf16* Q  = qb + (size_t)bh * (S_ * DH_);
  const bf16* Kp = kb + (size_t)bh * (S_ * DH_);

  // stage Q tile once (8 async16 per thread)
  const bf16* qg = Q + (size_t)(m0 + (tid >> 2)) * DH_ + (tid & 3) * 8;
  char* ql = (char*)Qs + tid * 16;
#pragma unroll
  for (int kt = 0; kt < 4; ++kt) {
    async16(qg + kt * 32,             ql + kt * 8192);
    async16(qg + kt * 32 + 64 * DH_,  ql + kt * 8192 + 4096);
  }

  const bf16* kg = Kp + (size_t)(tid >> 2) * DH_ + (tid & 3) * 8;
  char* kl = (char*)Ks + tid * 16;

  float sums[8] = {0.f, 0.f, 0.f, 0.f, 0.f, 0.f, 0.f, 0.f};

  for (int n0 = 0; n0 < S_; n0 += 128) {
    __syncthreads();
#pragma unroll
    for (int kt = 0; kt < 4; ++kt) {
      async16(kg + (size_t)n0 * DH_ + kt * 32,            kl + kt * 8192);
      async16(kg + (size_t)(n0 + 64) * DH_ + kt * 32,     kl + kt * 8192 + 4096);
    }
    __syncthreads();
    f32x4 acc[2][8] = {};
#pragma unroll
    for (int kt = 0; kt < 4; ++kt) {
      bf16x8 a[2], b[8];
#pragma unroll
      for (int i = 0; i < 2; ++i)
        a[i] = *(const bf16x8*)(Qs + kt * 4096 + (wm + i * 16 + c16) * 32 + quad * 8);
#pragma unroll
      for (int j = 0; j < 8; ++j)
        b[j] = *(const bf16x8*)(Ks + kt * 4096 + (j * 16 + c16) * 32 + quad * 8);
#pragma unroll
      for (int i = 0; i < 2; ++i)
#pragma unroll
        for (int j = 0; j < 8; ++j)
          acc[i][j] = __builtin_amdgcn_mfma_f32_16x16x32_bf16(a[i], b[j], acc[i][j], 0, 0, 0);
    }
#pragma unroll
    for (int i = 0; i < 2; ++i)
#pragma unroll
      for (int j = 0; j < 8; ++j)
#pragma unroll
        for (int r = 0; r < 4; ++r) {
          float sc = acc[i][j][r];
          int row = wm + i * 16 + quad * 4 + r;   // local Q row
          int col = j * 16 + c16;                 // local K row within n-tile
          sums[i * 4 + r] += __expf(sc);
          if (n0 + col == m0 + row)               // diagonal score
            diag[bh * S_ + m0 + row] = sc;
        }
  }

  // reduce partial sums across the 16 column-lanes sharing each row
#pragma unroll
  for (int t = 0; t < 8; ++t) {
    float s = sums[t];
    s += __shfl_xor(s, 1);
    s += __shfl_xor(s, 2);
    s += __shfl_xor(s, 4);
    s += __shfl_xor(s, 8);
    if (c16 == 0) {
      int i = t >> 2, r = t & 3;
      lse[bh * S_ + m0 + wm + i * 16 + quad * 4 + r] = __logf(s);
    }
  }
}

// ---------------------------------------------------------------------------
// t[b,s,h*128+d] = exp(diag - lse) * v   (8 bf16 per thread)
__global__ void wv_mul(const bf16* __restrict__ vb, const float* __restrict__ lse,
                       const float* __restrict__ diag, bf16* __restrict__ t) {
  int u = blockIdx.x * 256 + threadIdx.x;   // < 1048576
  int e = u * 8;
  int m = e >> 11;                          // b*2048+s
  int c = e & 2047;                         // h*128+d
  int g = ((m >> 11) * 16 + (c >> 7)) * 2048 + (m & 2047);
  float w = __expf(diag[g] - lse[g]);
  bf16x8 v = ((const bf16x8*)vb)[u];
  bf16x8 o;
#pragma unroll
  for (int r = 0; r < 8; ++r) o[r] = (bf16)((float)v[r] * w);
  ((bf16x8*)t)[u] = o;
}

// ---------------------------------------------------------------------------
// GEMM2: out(f32) = t(4096x2048 bf16) * Wo^T(2048x2048 bf16)
__global__ __launch_bounds__(256, 2) void gemm_out(
    const bf16* __restrict__ A, const bf16* __restrict__ Bm, float* __restrict__ C) {
  __shared__ alignas(16) bf16 As[128 * 32];
  __shared__ alignas(16) bf16 Bs[128 * 32];
  const int tid = threadIdx.x;
  const int lane = tid & 63, wv = tid >> 6;
  const int quad = lane >> 4, c16 = lane & 15;
  const int wm = (wv >> 1) * 64, wn = (wv & 1) * 64;
  const int m0 = blockIdx.y * 128, n0 = blockIdx.x * 128;

  const bf16* ag = A  + (size_t)(m0 + (tid >> 2)) * D_ + (tid & 3) * 8;
  const bf16* bg = Bm + (size_t)(n0 + (tid >> 2)) * D_ + (tid & 3) * 8;
  char* asl = (char*)As + tid * 16;
  char* bsl = (char*)Bs + tid * 16;

  f32x4 acc[4][4] = {};
  for (int k0 = 0; k0 < D_; k0 += 32) {
    __syncthreads();
    async16(ag + k0,            asl);
    async16(ag + k0 + 64 * D_,  asl + 4096);
    async16(bg + k0,            bsl);
    async16(bg + k0 + 64 * D_,  bsl + 4096);
    __syncthreads();
    bf16x8 af[4], bfr[4];
#pragma unroll
    for (int i = 0; i < 4; ++i)
      af[i] = *(const bf16x8*)(As + (wm + i * 16 + c16) * 32 + quad * 8);
#pragma unroll
    for (int j = 0; j < 4; ++j)
      bfr[j] = *(const bf16x8*)(Bs + (wn + j * 16 + c16) * 32 + quad * 8);
#pragma unroll
    for (int i = 0; i < 4; ++i)
#pragma unroll
      for (int j = 0; j < 4; ++j)
        acc[i][j] = __builtin_amdgcn_mfma_f32_16x16x32_bf16(af[i], bfr[j], acc[i][j], 0, 0, 0);
  }
#pragma unroll
  for (int i = 0; i < 4; ++i)
#pragma unroll
    for (int j = 0; j < 4; ++j)
#pragma unroll
      for (int r = 0; r < 4; ++r) {
        int gm = m0 + wm + i * 16 + quad * 4 + r;
        int gn = n0 + wn + j * 16 + c16;
        C[(size_t)gm * D_ + gn] = acc[i][j][r];
      }
}

// ---------------------------------------------------------------------------
extern "C" void kernel_launch(void* const* d_in, const int* in_sizes, int n_in,
                              void* d_out, int out_size, void* d_ws, size_t ws_size,
                              hipStream_t stream) {
  (void)in_sizes; (void)n_in; (void)out_size; (void)ws_size;
  const float* x  = (const float*)d_in[0];
  const float* rc = (const float*)d_in[1];
  const float* rs = (const float*)d_in[2];
  const float* Wq = (const float*)d_in[3];
  const float* Wk = (const float*)d_in[4];
  const float* Wv = (const float*)d_in[5];
  const float* Wo = (const float*)d_in[6];

  char* ws = (char*)d_ws;
  // workspace layout (bytes):
  bf16* xb   = (bf16*)ws;                          // 16 MB (x bf16; reused as t)
  bf16* wqkv = (bf16*)(ws + 16777216);             // 24 MB (6144x2048)
  bf16* wob  = (bf16*)(ws + 16777216 + 25165824);  // 8 MB
  bf16* qb   = (bf16*)(ws + 16777216 + 25165824 + 8388608);   // 16 MB
  bf16* kb   = qb + 8388608;                       // 16 MB
  bf16* vb   = kb + 8388608;                       // 16 MB
  float* lse = (float*)(vb + 8388608);             // 256 KB
  float* dia = lse + 65536;                        // 256 KB
  // total ~96.5 MB of d_ws

  cvt_bf16<<<8192, 256, 0, stream>>>(x,  xb);
  cvt_bf16<<<4096, 256, 0, stream>>>(Wq, wqkv);
  cvt_bf16<<<4096, 256, 0, stream>>>(Wk, wqkv + 4194304);
  cvt_bf16<<<4096, 256, 0, stream>>>(Wv, wqkv + 8388608);
  cvt_bf16<<<4096, 256, 0, stream>>>(Wo, wob);

  gemm_qkv<<<dim3(48, 32), 256, 0, stream>>>(xb, wqkv, qb, kb, vb);
  rope_kernel<<<16384, 256, 0, stream>>>(qb, kb, rc, rs);
  score_lse<<<dim3(16, 32), 256, 0, stream>>>(qb, kb, lse, dia);
  wv_mul<<<4096, 256, 0, stream>>>(vb, lse, dia, xb /* t reuses xb */);
  gemm_out<<<dim3(16, 32), 256, 0, stream>>>(xb, wob, (float*)d_out);
}